// Round 2
// baseline (564.201 us; speedup 1.0000x reference)
//
#include <hip/hip_runtime.h>
#include <hip/hip_bf16.h>

#define UHG_EPS 1e-9
#define ZDIM 128

#define EDGE_BLOCKS 1024   // fallback gather path
#define NODE_BLOCKS 1024
#define BLOCK 256

// ---- binned path geometry ----
#define PART_SHIFT 13               // 8192 nodes per partition (64 KB of float2)
#define PART_SIZE (1 << PART_SHIFT)
#define P_MAX 25                    // 25*8192 = 204800 >= 200000
#define NBINS_MAX (P_MAX * P_MAX)   // 625
#define STAGE_CAP 48                // u32 slots per bucket in scatter LDS (120 KB total)
#define CHUNK 32                    // flush granularity (128 B)
#define SCAT_BLOCKS 256             // one block per CU; each streams a contiguous edge range

// ws layout:
//   [0      , 16 KB) : double prox partials (nbins or EDGE_BLOCKS entries)
//   [16 KB  , 24 KB) : double comp partials (one per node block)
//   [24 KB  , 32 KB) : u32 bin cursors (nbins <= 625)
//   [32 KB  , +N*8 ) : float2 table[N] (compact x,y per node)
//   [ ...          ) : u32 gbins[nbins][bincap] (routed packed edges, ~63 MB)
#define PROX_OFF 0
#define COMP_OFF (16 * 1024)
#define GCUR_OFF (24 * 1024)
#define TABLE_OFF (32 * 1024)

typedef float vfloat2 __attribute__((ext_vector_type(2)));
typedef int vint4 __attribute__((ext_vector_type(4)));

// CK-style asm-declared buffer load (fallback gather path).
__device__ vfloat2 llvm_amdgcn_raw_buffer_load_v2f32(vint4 rsrc, int voffset, int soffset,
                                                     int cpol) __asm("llvm.amdgcn.raw.buffer.load.v2f32");

__device__ __forceinline__ vint4 make_srd(const void* base, unsigned int bytes) {
    union { const void* p; unsigned int w[2]; } pb;
    pb.p = base;
    vint4 r;
    r.x = (int)pb.w[0];
    r.y = (int)pb.w[1];
    r.z = (int)bytes;
    r.w = 0x00020000;
    return r;
}

// ---------------- device helpers ----------------

__device__ __forceinline__ double safe_den(double den) {
    return copysign(fmax(fabs(den), UHG_EPS), den);
}

__device__ __forceinline__ double quad_xy(vfloat2 a, vfloat2 b) {
    double xa = a.x, ya = a.y, xb = b.x, yb = b.y;
    double aa = 1.0 - (xa * xa + ya * ya);
    double bb = 1.0 - (xb * xb + yb * yb);
    double ab = 1.0 - (xa * xb + ya * yb);
    double den = aa * bb;
    double num = ab * ab - den;
    return num / safe_den(den);
}

__device__ __forceinline__ double block_reduce(double v, double* sh) {
    int lane = threadIdx.x & 63;
    int wid = threadIdx.x >> 6;
    v += __shfl_down(v, 32);
    v += __shfl_down(v, 16);
    v += __shfl_down(v, 8);
    v += __shfl_down(v, 4);
    v += __shfl_down(v, 2);
    v += __shfl_down(v, 1);
    if (lane == 0) sh[wid] = v;
    __syncthreads();
    double r = 0.0;
    if (wid == 0) {
        int nw = blockDim.x >> 6;
        r = (lane < nw) ? sh[lane] : 0.0;
        r += __shfl_down(r, 4);
        r += __shfl_down(r, 2);
        r += __shfl_down(r, 1);
    }
    __syncthreads();
    return r;
}

// ---------------- kernels ----------------

// Build compact (x,y) table + compactness partials; also zero the bin cursors.
__global__ __launch_bounds__(BLOCK) void node_kernel(const float* __restrict__ z,
                                                     vfloat2* __restrict__ table,
                                                     double* __restrict__ comp_partials, int N,
                                                     unsigned* __restrict__ gcur, int nbins) {
    __shared__ double sh[8];
    if (gcur && blockIdx.x == 0) {
        for (int j = threadIdx.x; j < nbins; j += BLOCK) gcur[j] = 0u;
    }
    const vfloat2* zp = (const vfloat2*)z;
    double local = 0.0;
    for (int i = blockIdx.x * BLOCK + threadIdx.x; i < N; i += NODE_BLOCKS * BLOCK) {
        vfloat2 v = zp[(size_t)i * (ZDIM / 2)];
        if (table) table[i] = v;
        double x = v.x, y = v.y;
        double aa = 1.0 - (x * x + y * y);
        local += (1.0 - aa) / safe_den(aa);   // ab=1, bb=1 against origin
    }
    double tot = block_reduce(local, sh);
    if (threadIdx.x == 0) comp_partials[blockIdx.x] = tot;
}

// Phase A: route every edge into bin (src>>13)*P + (dst>>13), payload = one u32
// (src_local | dst_local<<13). LDS-staged 32-entry chunk flushes keep global
// writes as coalesced 128B bursts — a direct per-edge scatter would be 12.8M
// random 4B stores and hit the exact same ~0.34 req/cyc/CU wall we're escaping.
// Batch-synchronous: append batch of 512 -> barrier -> flush full chunks -> barrier.
__global__ __launch_bounds__(BLOCK) void scatter_kernel(const int* __restrict__ src,
                                                        const int* __restrict__ dst, int E,
                                                        int P, int nbins,
                                                        unsigned* __restrict__ gcur,
                                                        unsigned* __restrict__ gbins, int bincap) {
    __shared__ unsigned cnt[NBINS_MAX];
    __shared__ unsigned stage[NBINS_MAX][STAGE_CAP];   // 120 KB
    const int tid = threadIdx.x;

    for (int b = tid; b < nbins; b += BLOCK) cnt[b] = 0u;
    __syncthreads();

    // contiguous per-block edge range
    const int e0 = (int)((long)blockIdx.x * E / SCAT_BLOCKS);
    const int e1 = (int)((long)(blockIdx.x + 1) * E / SCAT_BLOCKS);

    for (int base = e0; base < e1; base += 2 * BLOCK) {
#pragma unroll
        for (int k = 0; k < 2; ++k) {
            int i = base + k * BLOCK + tid;
            if (i < e1) {
                int s = __builtin_nontemporal_load(src + i);
                int d = __builtin_nontemporal_load(dst + i);
                int bin = (s >> PART_SHIFT) * P + (d >> PART_SHIFT);
                unsigned val = (unsigned)(s & (PART_SIZE - 1)) |
                               ((unsigned)(d & (PART_SIZE - 1)) << PART_SHIFT);
                unsigned slot = atomicAdd(&cnt[bin], 1u);
                if (slot < STAGE_CAP) {
                    stage[bin][slot] = val;
                } else {
                    // statistically unreachable for uniform edges (Poisson tail);
                    // correctness fallback: direct global append.
                    unsigned pos = atomicAdd(&gcur[bin], 1u);
                    if (pos < (unsigned)bincap) gbins[(size_t)bin * bincap + pos] = val;
                }
            }
        }
        __syncthreads();
        // flush one full chunk per over-full bucket (each bucket owned by one thread)
        for (int b = tid; b < nbins; b += BLOCK) {
            unsigned n = cnt[b];
            if (n >= CHUNK) {
                unsigned m = n < STAGE_CAP ? n : STAGE_CAP;   // staged entries
                unsigned pos = atomicAdd(&gcur[b], (unsigned)CHUNK);
                unsigned* out = gbins + (size_t)b * bincap + pos;
#pragma unroll
                for (int j = 0; j < CHUNK / 4; ++j) {
                    uint4 vv = *(const uint4*)&stage[b][4 * j];   // stage rows 192B: 16B-aligned
                    *(uint4*)(out + 4 * j) = vv;                  // pos % 32 == 0 in steady state
                }
                unsigned r = m - CHUNK;
                for (unsigned j = 0; j < r; ++j) stage[b][j] = stage[b][CHUNK + j];
                cnt[b] = r;
            }
        }
        __syncthreads();
    }
    // tail flush (partial chunks)
    for (int b = tid; b < nbins; b += BLOCK) {
        unsigned n = cnt[b];
        n = n < STAGE_CAP ? n : STAGE_CAP;
        if (n) {
            unsigned pos = atomicAdd(&gcur[b], n);
            unsigned* out = gbins + (size_t)b * bincap + pos;
            for (unsigned j = 0; j < n; ++j) out[j] = stage[b][j];
        }
    }
}

// Phase B: one block per bin. Both endpoint partitions live in LDS (128 KB),
// so the 2 random lookups per edge are ~6-cycle ds_reads instead of requests
// into the saturated L2 gather path. Edge payload stream is fully coalesced.
__global__ __launch_bounds__(BLOCK) void binned_edge_kernel(const vfloat2* __restrict__ table,
                                                            int N, int P,
                                                            const unsigned* __restrict__ gcur,
                                                            const unsigned* __restrict__ gbins,
                                                            int bincap,
                                                            double* __restrict__ prox_partials) {
    __shared__ vfloat2 pts[2][PART_SIZE];   // 128 KB
    __shared__ double sh[8];
    const int bin = blockIdx.x;
    const int sp = bin / P, dp = bin % P;
    const int tid = threadIdx.x;

    for (int j = tid; j < PART_SIZE; j += BLOCK) {
        int gs = (sp << PART_SHIFT) + j;
        int gd = (dp << PART_SHIFT) + j;
        vfloat2 zv = {0.0f, 0.0f};
        pts[0][j] = (gs < N) ? table[gs] : zv;
        pts[1][j] = (gd < N) ? table[gd] : zv;
    }
    __syncthreads();

    const unsigned len = gcur[bin];
    const unsigned* eb = gbins + (size_t)bin * bincap;
    double local = 0.0;
    for (unsigned i = tid; i < len; i += BLOCK) {
        unsigned v = eb[i];
        vfloat2 a = pts[0][v & (PART_SIZE - 1u)];
        vfloat2 b = pts[1][(v >> PART_SHIFT) & (PART_SIZE - 1u)];
        local += quad_xy(a, b);
    }
    double tot = block_reduce(local, sh);
    if (tid == 0) prox_partials[bin] = tot;
}

// -------- fallback gather path (verified round-1 kernel, unchanged) --------
#define GATHER8(dsta, i0, i1)                                                   \
    dsta[0] = llvm_amdgcn_raw_buffer_load_v2f32(srd, (i0).x << SHIFT, 0, 1);    \
    dsta[1] = llvm_amdgcn_raw_buffer_load_v2f32(srd, (i0).y << SHIFT, 0, 1);    \
    dsta[2] = llvm_amdgcn_raw_buffer_load_v2f32(srd, (i0).z << SHIFT, 0, 1);    \
    dsta[3] = llvm_amdgcn_raw_buffer_load_v2f32(srd, (i0).w << SHIFT, 0, 1);    \
    dsta[4] = llvm_amdgcn_raw_buffer_load_v2f32(srd, (i1).x << SHIFT, 0, 1);    \
    dsta[5] = llvm_amdgcn_raw_buffer_load_v2f32(srd, (i1).y << SHIFT, 0, 1);    \
    dsta[6] = llvm_amdgcn_raw_buffer_load_v2f32(srd, (i1).z << SHIFT, 0, 1);    \
    dsta[7] = llvm_amdgcn_raw_buffer_load_v2f32(srd, (i1).w << SHIFT, 0, 1);

template <int COMPACT>
__global__ __launch_bounds__(BLOCK) void edge_kernel(const vint4* __restrict__ src4,
                                                     const vint4* __restrict__ dst4, int nvec,
                                                     const int* __restrict__ src,
                                                     const int* __restrict__ dst, int E,
                                                     const void* __restrict__ xy, int N,
                                                     double* __restrict__ prox_partials) {
    __shared__ double sh[8];
    double local = 0.0;
    int tid = blockIdx.x * BLOCK + threadIdx.x;
    const int gstride = EDGE_BLOCKS * BLOCK;
    const int SHIFT = COMPACT ? 3 : 9;

    vint4 srd = make_srd(xy, COMPACT ? (unsigned int)N * 8u : (unsigned int)N * 512u);

    int nvec2 = nvec / 2;
    int v0 = tid;
    bool p0 = v0 < nvec2;
    int v1 = v0 + gstride;
    bool p1 = v1 < nvec2;

    vint4 is0 = {}, is1 = {}, id0 = {}, id1 = {};
    vfloat2 ca[8] = {}, cb[8] = {};
    vfloat2 na[8] = {}, nb[8] = {};

    if (p0) {
        vint4 s0 = __builtin_nontemporal_load(src4 + 2 * (long)v0);
        vint4 s1 = __builtin_nontemporal_load(src4 + 2 * (long)v0 + 1);
        vint4 d0 = __builtin_nontemporal_load(dst4 + 2 * (long)v0);
        vint4 d1 = __builtin_nontemporal_load(dst4 + 2 * (long)v0 + 1);
        GATHER8(ca, s0, s1);
        GATHER8(cb, d0, d1);
    }
    if (p1) {
        is0 = __builtin_nontemporal_load(src4 + 2 * (long)v1);
        is1 = __builtin_nontemporal_load(src4 + 2 * (long)v1 + 1);
        id0 = __builtin_nontemporal_load(dst4 + 2 * (long)v1);
        id1 = __builtin_nontemporal_load(dst4 + 2 * (long)v1 + 1);
    }

    while (p0) {
        if (p1) {
            GATHER8(na, is0, is1);
            GATHER8(nb, id0, id1);
        }
        int v2 = v1 + gstride;
        bool p2 = v2 < nvec2;
        if (p2) {
            is0 = __builtin_nontemporal_load(src4 + 2 * (long)v2);
            is1 = __builtin_nontemporal_load(src4 + 2 * (long)v2 + 1);
            id0 = __builtin_nontemporal_load(dst4 + 2 * (long)v2);
            id1 = __builtin_nontemporal_load(dst4 + 2 * (long)v2 + 1);
        }
        __builtin_amdgcn_sched_barrier(0);
#pragma unroll
        for (int i = 0; i < 8; ++i) local += quad_xy(ca[i], cb[i]);
#pragma unroll
        for (int i = 0; i < 8; ++i) { ca[i] = na[i]; cb[i] = nb[i]; }
        p0 = p1;
        v1 = v2;
        p1 = p2;
    }

    for (int e = 8 * nvec2 + tid; e < E; e += gstride) {
        vfloat2 a = llvm_amdgcn_raw_buffer_load_v2f32(srd, src[e] << SHIFT, 0, 1);
        vfloat2 b = llvm_amdgcn_raw_buffer_load_v2f32(srd, dst[e] << SHIFT, 0, 1);
        local += quad_xy(a, b);
    }
    double tot = block_reduce(local, sh);
    if (threadIdx.x == 0) prox_partials[blockIdx.x] = tot;
}

// Sum partials + spread over first min(10,E) edges + combine. One block of 256.
__global__ __launch_bounds__(BLOCK) void finalize_kernel(const int* __restrict__ src,
                                                         const int* __restrict__ dst,
                                                         const float* __restrict__ z,
                                                         const double* __restrict__ prox_partials,
                                                         int nprox,
                                                         const double* __restrict__ comp_partials,
                                                         float* __restrict__ out, int N, int E) {
    __shared__ double sh[8];
    int t = threadIdx.x;

    double pl = 0.0;
    for (int i = t; i < nprox; i += BLOCK) pl += prox_partials[i];
    double prox = block_reduce(pl, sh);

    double cl = 0.0;
    for (int i = t; i < NODE_BLOCKS; i += BLOCK) cl += comp_partials[i];
    double comp = block_reduce(cl, sh);

    int n_sp = E < 10 ? E : 10;
    double sl = 0.0;
    if (t < n_sp) {
        int s = src[t], d = dst[t];
        double xa = z[(size_t)s * ZDIM], ya = z[(size_t)s * ZDIM + 1];
        double xb = z[(size_t)d * ZDIM], yb = z[(size_t)d * ZDIM + 1];
        double aa = -(ya * ya + xa * xa);
        double bb = -(yb * yb + xb * xb);
        double ab = -(ya * yb + xa * xb);
        double den = aa * bb;
        sl = (ab * ab - den) / safe_den(den);
    }
    double spread = block_reduce(sl, sh);

    if (t == 0) {
        double loss = prox / (double)E + comp / (double)N;
        if (n_sp > 0) loss += 0.1 * (spread / (double)n_sp);
        out[0] = (float)loss;
    }
}

// ---------------- launch ----------------

extern "C" void kernel_launch(void* const* d_in, const int* in_sizes, int n_in,
                              void* d_out, int out_size, void* d_ws, size_t ws_size,
                              hipStream_t stream) {
    const float* z = (const float*)d_in[0];
    const int* edge_index = (const int*)d_in[1];
    float* out = (float*)d_out;

    const int N = in_sizes[0] / ZDIM;
    const int E = in_sizes[1] / 2;
    const int* src = edge_index;
    const int* dst = edge_index + (size_t)E;

    double* prox_partials = (double*)((char*)d_ws + PROX_OFF);
    double* comp_partials = (double*)((char*)d_ws + COMP_OFF);
    unsigned* gcur = (unsigned*)((char*)d_ws + GCUR_OFF);
    vfloat2* table = (vfloat2*)((char*)d_ws + TABLE_OFF);
    bool use_table = ws_size >= TABLE_OFF + (size_t)N * sizeof(vfloat2);

    // binned-path feasibility
    const int P = (N + PART_SIZE - 1) >> PART_SHIFT;
    const int nbins = P * P;
    int bincap = 0;
    size_t gbins_off = TABLE_OFF + (((size_t)N * 8 + 255) & ~(size_t)255);
    bool use_binned = false;
    unsigned* gbins = nullptr;
    if (use_table && P >= 1 && P <= P_MAX && nbins <= NBINS_MAX && E > nbins * 64) {
        int mean = E / nbins;
        bincap = (mean + mean / 8 + 2048 + 31) & ~31;   // ~28 sigma margin, 32-aligned
        size_t need = gbins_off + (size_t)nbins * (size_t)bincap * 4u;
        if (ws_size >= need) {
            use_binned = true;
            gbins = (unsigned*)((char*)d_ws + gbins_off);
        }
    }

    node_kernel<<<NODE_BLOCKS, BLOCK, 0, stream>>>(z, use_table ? table : nullptr,
                                                   comp_partials,
                                                   N, use_binned ? gcur : nullptr, nbins);

    if (use_binned) {
        scatter_kernel<<<SCAT_BLOCKS, BLOCK, 0, stream>>>(src, dst, E, P, nbins, gcur, gbins,
                                                          bincap);
        binned_edge_kernel<<<nbins, BLOCK, 0, stream>>>(table, N, P, gcur, gbins, bincap,
                                                        prox_partials);
        finalize_kernel<<<1, BLOCK, 0, stream>>>(src, dst, z, prox_partials, nbins,
                                                 comp_partials, out, N, E);
    } else {
        int nvec = E / 4;
        if (use_table) {
            edge_kernel<1><<<EDGE_BLOCKS, BLOCK, 0, stream>>>((const vint4*)src,
                                                              (const vint4*)dst, nvec, src, dst,
                                                              E, table, N, prox_partials);
        } else {
            edge_kernel<0><<<EDGE_BLOCKS, BLOCK, 0, stream>>>((const vint4*)src,
                                                              (const vint4*)dst, nvec, src, dst,
                                                              E, z, N, prox_partials);
        }
        finalize_kernel<<<1, BLOCK, 0, stream>>>(src, dst, z, prox_partials, EDGE_BLOCKS,
                                                 comp_partials, out, N, E);
    }
}

// Round 3
// 296.082 us; speedup vs baseline: 1.9056x; 1.9056x over previous
//
#include <hip/hip_runtime.h>
#include <hip/hip_bf16.h>

#define UHG_EPS 1e-9
#define ZDIM 128

#define EDGE_BLOCKS 1024   // fallback gather path
#define NODE_BLOCKS 1024
#define BLOCK 256

// ---- binned path geometry ----
#define PART_SHIFT 13               // 8192 nodes per partition (64 KB of float2)
#define PART_SIZE (1 << PART_SHIFT)
#define P_MAX 25                    // 25*8192 = 204800 >= 200000
#define NBINS_MAX (P_MAX * P_MAX)   // 625
#define STAGE_CAP 56                // u32 slots per bucket (625*56*4 = 140 KB)
#define CHUNK 16                    // flush granularity (64 B, always aligned)
#define SCAT_BLOCKS 256
#define SBLOCK 512                  // scatter block: 8 waves/CU
#define BBLOCK 1024                 // binned-edge block: 16 waves/CU
#define SENTINEL 0xFFFFFFFFu
#define OVGUARD 4096u               // max overflow entries per bin (top region)

// ws layout:
//   [0      , 16 KB) : double prox partials (nbins or EDGE_BLOCKS entries)
//   [16 KB  , 24 KB) : double comp partials (one per node block)
//   [24 KB  , 32 KB) : u32 cursors: gcur[0..nbins)=bottom, gcur[nbins..2*nbins)=top
//   [32 KB  , +N*8 ) : float2 table[N] (compact x,y per node)
//   [ ...          ) : u32 gbins[nbins][bincap] (routed packed edges)
#define PROX_OFF 0
#define COMP_OFF (16 * 1024)
#define GCUR_OFF (24 * 1024)
#define TABLE_OFF (32 * 1024)

typedef float vfloat2 __attribute__((ext_vector_type(2)));
typedef int vint4 __attribute__((ext_vector_type(4)));
typedef unsigned uvec4 __attribute__((ext_vector_type(4)));

// CK-style asm-declared buffer load (fallback gather path).
__device__ vfloat2 llvm_amdgcn_raw_buffer_load_v2f32(vint4 rsrc, int voffset, int soffset,
                                                     int cpol) __asm("llvm.amdgcn.raw.buffer.load.v2f32");

__device__ __forceinline__ vint4 make_srd(const void* base, unsigned int bytes) {
    union { const void* p; unsigned int w[2]; } pb;
    pb.p = base;
    vint4 r;
    r.x = (int)pb.w[0];
    r.y = (int)pb.w[1];
    r.z = (int)bytes;
    r.w = 0x00020000;
    return r;
}

// ---------------- device helpers ----------------

__device__ __forceinline__ double safe_den(double den) {
    return copysign(fmax(fabs(den), UHG_EPS), den);
}

__device__ __forceinline__ double quad_xy(vfloat2 a, vfloat2 b) {
    double xa = a.x, ya = a.y, xb = b.x, yb = b.y;
    double aa = 1.0 - (xa * xa + ya * ya);
    double bb = 1.0 - (xb * xb + yb * yb);
    double ab = 1.0 - (xa * xb + ya * yb);
    double den = aa * bb;
    double num = ab * ab - den;
    return num / safe_den(den);
}

// Block reduction for up to 16 waves: returns total on thread 0. sh >= 16 doubles.
__device__ __forceinline__ double block_reduce(double v, double* sh) {
    int lane = threadIdx.x & 63;
    int wid = threadIdx.x >> 6;
    v += __shfl_down(v, 32);
    v += __shfl_down(v, 16);
    v += __shfl_down(v, 8);
    v += __shfl_down(v, 4);
    v += __shfl_down(v, 2);
    v += __shfl_down(v, 1);
    if (lane == 0) sh[wid] = v;
    __syncthreads();
    double r = 0.0;
    if (wid == 0) {
        int nw = (int)(blockDim.x >> 6);
        r = (lane < nw) ? sh[lane] : 0.0;
        r += __shfl_down(r, 8);
        r += __shfl_down(r, 4);
        r += __shfl_down(r, 2);
        r += __shfl_down(r, 1);
    }
    __syncthreads();
    return r;
}

// ---------------- kernels ----------------

// Build compact (x,y) table + compactness partials; zero both cursor arrays.
__global__ __launch_bounds__(BLOCK) void node_kernel(const float* __restrict__ z,
                                                     vfloat2* __restrict__ table,
                                                     double* __restrict__ comp_partials, int N,
                                                     unsigned* __restrict__ gcur, int nbins) {
    __shared__ double sh[16];
    if (gcur && blockIdx.x == 0) {
        for (int j = threadIdx.x; j < 2 * nbins; j += BLOCK) gcur[j] = 0u;
    }
    const vfloat2* zp = (const vfloat2*)z;
    double local = 0.0;
    for (int i = blockIdx.x * BLOCK + threadIdx.x; i < N; i += NODE_BLOCKS * BLOCK) {
        vfloat2 v = zp[(size_t)i * (ZDIM / 2)];
        if (table) table[i] = v;
        double x = v.x, y = v.y;
        double aa = 1.0 - (x * x + y * y);
        local += (1.0 - aa) / safe_den(aa);   // ab=1, bb=1 against origin
    }
    double tot = block_reduce(local, sh);
    if (threadIdx.x == 0) comp_partials[blockIdx.x] = tot;
}

// Phase A: route edges into bin (src>>13)*P + (dst>>13), payload u32
// (src_local | dst_local<<13). v2: 8 waves/CU, 4096-edge batches with index
// prefetch one batch ahead, 16-entry (64 B) aligned chunk flushes. Every bottom-
// cursor increment is exactly CHUNK, so uint4 stores stay 16B-aligned; final
// residues are sentinel-padded to a full chunk. Overflow -> top-of-bin region.
__global__ __launch_bounds__(SBLOCK) void scatter_kernel(const int* __restrict__ src,
                                                         const int* __restrict__ dst, int E,
                                                         int P, int nbins,
                                                         unsigned* __restrict__ gcur,
                                                         unsigned* __restrict__ gbins,
                                                         int bincap) {
    __shared__ unsigned cnt[NBINS_MAX];
    __shared__ __align__(16) unsigned stage[NBINS_MAX][STAGE_CAP];   // 140 KB
    const int tid = threadIdx.x;

    for (int b = tid; b < nbins; b += SBLOCK) cnt[b] = 0u;
    __syncthreads();

#define PROC_EDGE(S, D)                                                                   \
    {                                                                                     \
        int _bin = ((S) >> PART_SHIFT) * P + ((D) >> PART_SHIFT);                         \
        unsigned _val = (unsigned)((S) & (PART_SIZE - 1)) |                               \
                        ((unsigned)((D) & (PART_SIZE - 1)) << PART_SHIFT);                \
        unsigned _slot = atomicAdd(&cnt[_bin], 1u);                                       \
        if (_slot < (unsigned)STAGE_CAP) {                                                \
            stage[_bin][_slot] = _val;                                                    \
        } else {                                                                          \
            unsigned _hp = atomicAdd(&gcur[nbins + _bin], 1u);                            \
            if (_hp < OVGUARD)                                                            \
                gbins[(size_t)_bin * bincap + (bincap - 1 - (int)_hp)] = _val;            \
        }                                                                                 \
    }

    auto flush_bins = [&](bool final_pad) {
        for (int b = tid; b < nbins; b += SBLOCK) {
            unsigned n = cnt[b];
            unsigned m = n < (unsigned)STAGE_CAP ? n : (unsigned)STAGE_CAP;
            while (m >= (unsigned)CHUNK) {
                unsigned pos = atomicAdd(&gcur[b], (unsigned)CHUNK);
                if (pos + CHUNK <= (unsigned)bincap) {
                    unsigned* out = gbins + (size_t)b * bincap + pos;
#pragma unroll
                    for (int j = 0; j < CHUNK / 4; ++j)
                        *(uvec4*)(out + 4 * j) = *(const uvec4*)&stage[b][4 * j];
                } else {
                    for (int j = 0; j < CHUNK; ++j) {
                        unsigned hp = atomicAdd(&gcur[nbins + b], 1u);
                        if (hp < OVGUARD)
                            gbins[(size_t)b * bincap + (bincap - 1 - (int)hp)] = stage[b][j];
                    }
                }
                for (unsigned j = CHUNK; j < m; ++j) stage[b][j - CHUNK] = stage[b][j];
                m -= CHUNK;
            }
            if (final_pad && m > 0) {
                for (unsigned j = m; j < (unsigned)CHUNK; ++j) stage[b][j] = SENTINEL;
                unsigned pos = atomicAdd(&gcur[b], (unsigned)CHUNK);
                if (pos + CHUNK <= (unsigned)bincap) {
                    unsigned* out = gbins + (size_t)b * bincap + pos;
#pragma unroll
                    for (int j = 0; j < CHUNK / 4; ++j)
                        *(uvec4*)(out + 4 * j) = *(const uvec4*)&stage[b][4 * j];
                } else {
                    for (unsigned j = 0; j < m; ++j) {
                        unsigned hp = atomicAdd(&gcur[nbins + b], 1u);
                        if (hp < OVGUARD)
                            gbins[(size_t)b * bincap + (bincap - 1 - (int)hp)] = stage[b][j];
                    }
                }
                m = 0;
            }
            cnt[b] = m;
        }
    };

    // contiguous per-block edge range, 8-aligned start (last block takes the tail)
    long e0 = ((long)blockIdx.x * E / SCAT_BLOCKS) & ~7L;
    long e1 = (blockIdx.x == SCAT_BLOCKS - 1)
                  ? (long)E
                  : (((long)(blockIdx.x + 1) * E / SCAT_BLOCKS) & ~7L);
    long span = e1 - e0;
    long nbatch = span / (8 * SBLOCK);          // full 4096-edge batches
    long rem0 = e0 + nbatch * 8 * SBLOCK;

    const vint4* s4 = (const vint4*)(src + e0);
    const vint4* d4 = (const vint4*)(dst + e0);

    vint4 cs0 = {}, cs1 = {}, cd0 = {}, cd1 = {};
    if (nbatch > 0) {   // prologue: batch 0 indices
        cs0 = __builtin_nontemporal_load(s4 + 2 * tid);
        cs1 = __builtin_nontemporal_load(s4 + 2 * tid + 1);
        cd0 = __builtin_nontemporal_load(d4 + 2 * tid);
        cd1 = __builtin_nontemporal_load(d4 + 2 * tid + 1);
    }
    for (long k = 0; k < nbatch; ++k) {
        vint4 s0 = cs0, s1 = cs1, dd0 = cd0, dd1 = cd1;
        if (k + 1 < nbatch) {   // prefetch next batch before touching LDS
            long b4 = (k + 1) * (2 * SBLOCK) + 2 * tid;
            cs0 = __builtin_nontemporal_load(s4 + b4);
            cs1 = __builtin_nontemporal_load(s4 + b4 + 1);
            cd0 = __builtin_nontemporal_load(d4 + b4);
            cd1 = __builtin_nontemporal_load(d4 + b4 + 1);
        }
        __builtin_amdgcn_sched_barrier(0);
        PROC_EDGE(s0.x, dd0.x);
        PROC_EDGE(s0.y, dd0.y);
        PROC_EDGE(s0.z, dd0.z);
        PROC_EDGE(s0.w, dd0.w);
        PROC_EDGE(s1.x, dd1.x);
        PROC_EDGE(s1.y, dd1.y);
        PROC_EDGE(s1.z, dd1.z);
        PROC_EDGE(s1.w, dd1.w);
        __syncthreads();
        flush_bins(false);
        __syncthreads();
    }
    // remainder edges (scalar)
    for (long i = rem0 + tid; i < e1; i += SBLOCK) {
        int s = src[i], d = dst[i];
        PROC_EDGE(s, d);
    }
    __syncthreads();
    flush_bins(true);   // drain + sentinel-pad residues to full chunks
#undef PROC_EDGE
}

// Phase B: one block per bin, 16 waves. Both endpoint partitions in LDS (128 KB);
// random lookups are ds_reads. 4-deep unrolled payload stream for MLP/ILP.
__global__ __launch_bounds__(BBLOCK) void binned_edge_kernel(const vfloat2* __restrict__ table,
                                                             int N, int P,
                                                             const unsigned* __restrict__ gcur,
                                                             const unsigned* __restrict__ gbins,
                                                             int bincap,
                                                             double* __restrict__ prox_partials) {
    __shared__ vfloat2 pts[2][PART_SIZE];   // 128 KB
    __shared__ double sh[16];
    const int bin = blockIdx.x;
    const int sp = bin / P, dp = bin % P;
    const int tid = threadIdx.x;
    const int nbins = P * P;

    for (int j = tid; j < PART_SIZE; j += BBLOCK) {
        int gs = (sp << PART_SHIFT) + j;
        int gd = (dp << PART_SHIFT) + j;
        vfloat2 zv = {0.0f, 0.0f};
        pts[0][j] = (gs < N) ? table[gs] : zv;
        pts[1][j] = (gd < N) ? table[gd] : zv;
    }
    __syncthreads();

    unsigned lo = gcur[bin];
    if (lo > (unsigned)bincap) lo = (unsigned)bincap;
    unsigned hi = gcur[nbins + bin];
    if (hi > OVGUARD) hi = OVGUARD;
    const unsigned* eb = gbins + (size_t)bin * bincap;

    double local = 0.0;
    unsigned i = tid;
    for (; i + 3u * BBLOCK < lo; i += 4u * BBLOCK) {
        unsigned v0 = __builtin_nontemporal_load(eb + i);
        unsigned v1 = __builtin_nontemporal_load(eb + i + BBLOCK);
        unsigned v2 = __builtin_nontemporal_load(eb + i + 2u * BBLOCK);
        unsigned v3 = __builtin_nontemporal_load(eb + i + 3u * BBLOCK);
        vfloat2 a0 = pts[0][v0 & (PART_SIZE - 1u)], b0 = pts[1][(v0 >> PART_SHIFT) & (PART_SIZE - 1u)];
        vfloat2 a1 = pts[0][v1 & (PART_SIZE - 1u)], b1 = pts[1][(v1 >> PART_SHIFT) & (PART_SIZE - 1u)];
        vfloat2 a2 = pts[0][v2 & (PART_SIZE - 1u)], b2 = pts[1][(v2 >> PART_SHIFT) & (PART_SIZE - 1u)];
        vfloat2 a3 = pts[0][v3 & (PART_SIZE - 1u)], b3 = pts[1][(v3 >> PART_SHIFT) & (PART_SIZE - 1u)];
        if (v0 != SENTINEL) local += quad_xy(a0, b0);
        if (v1 != SENTINEL) local += quad_xy(a1, b1);
        if (v2 != SENTINEL) local += quad_xy(a2, b2);
        if (v3 != SENTINEL) local += quad_xy(a3, b3);
    }
    for (; i < lo; i += BBLOCK) {
        unsigned v = eb[i];
        if (v != SENTINEL)
            local += quad_xy(pts[0][v & (PART_SIZE - 1u)],
                             pts[1][(v >> PART_SHIFT) & (PART_SIZE - 1u)]);
    }
    for (unsigned j = tid; j < hi; j += BBLOCK) {   // overflow (top) region, no sentinels
        unsigned v = eb[bincap - 1 - (int)j];
        local += quad_xy(pts[0][v & (PART_SIZE - 1u)],
                         pts[1][(v >> PART_SHIFT) & (PART_SIZE - 1u)]);
    }
    double tot = block_reduce(local, sh);
    if (tid == 0) prox_partials[bin] = tot;
}

// -------- fallback gather path (verified round-1 kernel, unchanged) --------
#define GATHER8(dsta, i0, i1)                                                   \
    dsta[0] = llvm_amdgcn_raw_buffer_load_v2f32(srd, (i0).x << SHIFT, 0, 1);    \
    dsta[1] = llvm_amdgcn_raw_buffer_load_v2f32(srd, (i0).y << SHIFT, 0, 1);    \
    dsta[2] = llvm_amdgcn_raw_buffer_load_v2f32(srd, (i0).z << SHIFT, 0, 1);    \
    dsta[3] = llvm_amdgcn_raw_buffer_load_v2f32(srd, (i0).w << SHIFT, 0, 1);    \
    dsta[4] = llvm_amdgcn_raw_buffer_load_v2f32(srd, (i1).x << SHIFT, 0, 1);    \
    dsta[5] = llvm_amdgcn_raw_buffer_load_v2f32(srd, (i1).y << SHIFT, 0, 1);    \
    dsta[6] = llvm_amdgcn_raw_buffer_load_v2f32(srd, (i1).z << SHIFT, 0, 1);    \
    dsta[7] = llvm_amdgcn_raw_buffer_load_v2f32(srd, (i1).w << SHIFT, 0, 1);

template <int COMPACT>
__global__ __launch_bounds__(BLOCK) void edge_kernel(const vint4* __restrict__ src4,
                                                     const vint4* __restrict__ dst4, int nvec,
                                                     const int* __restrict__ src,
                                                     const int* __restrict__ dst, int E,
                                                     const void* __restrict__ xy, int N,
                                                     double* __restrict__ prox_partials) {
    __shared__ double sh[16];
    double local = 0.0;
    int tid = blockIdx.x * BLOCK + threadIdx.x;
    const int gstride = EDGE_BLOCKS * BLOCK;
    const int SHIFT = COMPACT ? 3 : 9;

    vint4 srd = make_srd(xy, COMPACT ? (unsigned int)N * 8u : (unsigned int)N * 512u);

    int nvec2 = nvec / 2;
    int v0 = tid;
    bool p0 = v0 < nvec2;
    int v1 = v0 + gstride;
    bool p1 = v1 < nvec2;

    vint4 is0 = {}, is1 = {}, id0 = {}, id1 = {};
    vfloat2 ca[8] = {}, cb[8] = {};
    vfloat2 na[8] = {}, nb[8] = {};

    if (p0) {
        vint4 s0 = __builtin_nontemporal_load(src4 + 2 * (long)v0);
        vint4 s1 = __builtin_nontemporal_load(src4 + 2 * (long)v0 + 1);
        vint4 d0 = __builtin_nontemporal_load(dst4 + 2 * (long)v0);
        vint4 d1 = __builtin_nontemporal_load(dst4 + 2 * (long)v0 + 1);
        GATHER8(ca, s0, s1);
        GATHER8(cb, d0, d1);
    }
    if (p1) {
        is0 = __builtin_nontemporal_load(src4 + 2 * (long)v1);
        is1 = __builtin_nontemporal_load(src4 + 2 * (long)v1 + 1);
        id0 = __builtin_nontemporal_load(dst4 + 2 * (long)v1);
        id1 = __builtin_nontemporal_load(dst4 + 2 * (long)v1 + 1);
    }

    while (p0) {
        if (p1) {
            GATHER8(na, is0, is1);
            GATHER8(nb, id0, id1);
        }
        int v2 = v1 + gstride;
        bool p2 = v2 < nvec2;
        if (p2) {
            is0 = __builtin_nontemporal_load(src4 + 2 * (long)v2);
            is1 = __builtin_nontemporal_load(src4 + 2 * (long)v2 + 1);
            id0 = __builtin_nontemporal_load(dst4 + 2 * (long)v2);
            id1 = __builtin_nontemporal_load(dst4 + 2 * (long)v2 + 1);
        }
        __builtin_amdgcn_sched_barrier(0);
#pragma unroll
        for (int i = 0; i < 8; ++i) local += quad_xy(ca[i], cb[i]);
#pragma unroll
        for (int i = 0; i < 8; ++i) { ca[i] = na[i]; cb[i] = nb[i]; }
        p0 = p1;
        v1 = v2;
        p1 = p2;
    }

    for (int e = 8 * nvec2 + tid; e < E; e += gstride) {
        vfloat2 a = llvm_amdgcn_raw_buffer_load_v2f32(srd, src[e] << SHIFT, 0, 1);
        vfloat2 b = llvm_amdgcn_raw_buffer_load_v2f32(srd, dst[e] << SHIFT, 0, 1);
        local += quad_xy(a, b);
    }
    double tot = block_reduce(local, sh);
    if (threadIdx.x == 0) prox_partials[blockIdx.x] = tot;
}

// Sum partials + spread over first min(10,E) edges + combine. One block of 256.
__global__ __launch_bounds__(BLOCK) void finalize_kernel(const int* __restrict__ src,
                                                         const int* __restrict__ dst,
                                                         const float* __restrict__ z,
                                                         const double* __restrict__ prox_partials,
                                                         int nprox,
                                                         const double* __restrict__ comp_partials,
                                                         float* __restrict__ out, int N, int E) {
    __shared__ double sh[16];
    int t = threadIdx.x;

    double pl = 0.0;
    for (int i = t; i < nprox; i += BLOCK) pl += prox_partials[i];
    double prox = block_reduce(pl, sh);

    double cl = 0.0;
    for (int i = t; i < NODE_BLOCKS; i += BLOCK) cl += comp_partials[i];
    double comp = block_reduce(cl, sh);

    int n_sp = E < 10 ? E : 10;
    double sl = 0.0;
    if (t < n_sp) {
        int s = src[t], d = dst[t];
        double xa = z[(size_t)s * ZDIM], ya = z[(size_t)s * ZDIM + 1];
        double xb = z[(size_t)d * ZDIM], yb = z[(size_t)d * ZDIM + 1];
        double aa = -(ya * ya + xa * xa);
        double bb = -(yb * yb + xb * xb);
        double ab = -(ya * yb + xa * xb);
        double den = aa * bb;
        sl = (ab * ab - den) / safe_den(den);
    }
    double spread = block_reduce(sl, sh);

    if (t == 0) {
        double loss = prox / (double)E + comp / (double)N;
        if (n_sp > 0) loss += 0.1 * (spread / (double)n_sp);
        out[0] = (float)loss;
    }
}

// ---------------- launch ----------------

extern "C" void kernel_launch(void* const* d_in, const int* in_sizes, int n_in,
                              void* d_out, int out_size, void* d_ws, size_t ws_size,
                              hipStream_t stream) {
    const float* z = (const float*)d_in[0];
    const int* edge_index = (const int*)d_in[1];
    float* out = (float*)d_out;

    const int N = in_sizes[0] / ZDIM;
    const int E = in_sizes[1] / 2;
    const int* src = edge_index;
    const int* dst = edge_index + (size_t)E;

    double* prox_partials = (double*)((char*)d_ws + PROX_OFF);
    double* comp_partials = (double*)((char*)d_ws + COMP_OFF);
    unsigned* gcur = (unsigned*)((char*)d_ws + GCUR_OFF);
    vfloat2* table = (vfloat2*)((char*)d_ws + TABLE_OFF);
    bool use_table = ws_size >= TABLE_OFF + (size_t)N * sizeof(vfloat2);

    // binned-path feasibility (ws-adaptive bincap)
    const int P = (N + PART_SIZE - 1) >> PART_SHIFT;
    const int nbins = P * P;
    size_t gbins_off = TABLE_OFF + (((size_t)N * 8 + 255) & ~(size_t)255);
    bool use_binned = false;
    unsigned* gbins = nullptr;
    int bincap = 0;
    if (use_table && P >= 1 && P <= P_MAX && nbins <= NBINS_MAX && E > nbins * 64 &&
        ws_size > gbins_off) {
        int mean = E / nbins;
        int pad = SCAT_BLOCKS * (CHUNK - 1);                 // worst-case sentinel pad
        int cap_want = (mean + pad + 2048 + 31) & ~31;
        size_t avail = ws_size - gbins_off;
        int cap_fit = (int)((avail / ((size_t)nbins * 4)) & ~(size_t)31);
        bincap = cap_fit < cap_want ? cap_fit : cap_want;
        if (bincap >= mean + pad + 512) {
            use_binned = true;
            gbins = (unsigned*)((char*)d_ws + gbins_off);
        }
    }

    node_kernel<<<NODE_BLOCKS, BLOCK, 0, stream>>>(z, use_table ? table : nullptr,
                                                   comp_partials,
                                                   N, use_binned ? gcur : nullptr, nbins);

    if (use_binned) {
        scatter_kernel<<<SCAT_BLOCKS, SBLOCK, 0, stream>>>(src, dst, E, P, nbins, gcur, gbins,
                                                           bincap);
        binned_edge_kernel<<<nbins, BBLOCK, 0, stream>>>(table, N, P, gcur, gbins, bincap,
                                                         prox_partials);
        finalize_kernel<<<1, BLOCK, 0, stream>>>(src, dst, z, prox_partials, nbins,
                                                 comp_partials, out, N, E);
    } else {
        int nvec = E / 4;
        if (use_table) {
            edge_kernel<1><<<EDGE_BLOCKS, BLOCK, 0, stream>>>((const vint4*)src,
                                                              (const vint4*)dst, nvec, src, dst,
                                                              E, table, N, prox_partials);
        } else {
            edge_kernel<0><<<EDGE_BLOCKS, BLOCK, 0, stream>>>((const vint4*)src,
                                                              (const vint4*)dst, nvec, src, dst,
                                                              E, z, N, prox_partials);
        }
        finalize_kernel<<<1, BLOCK, 0, stream>>>(src, dst, z, prox_partials, EDGE_BLOCKS,
                                                 comp_partials, out, N, E);
    }
}

// Round 4
// 286.417 us; speedup vs baseline: 1.9699x; 1.0337x over previous
//
#include <hip/hip_runtime.h>
#include <hip/hip_bf16.h>

#define UHG_EPS 1e-9
#define ZDIM 128

#define EDGE_BLOCKS 1024   // fallback gather path
#define NODE_BLOCKS 1024
#define BLOCK 256

// ---- binned path geometry ----
#define PART_SHIFT 13               // 8192 nodes per partition (64 KB of float2)
#define PART_SIZE (1 << PART_SHIFT)
#define P_MAX 25                    // 25*8192 = 204800 >= 200000
#define NBINS_MAX (P_MAX * P_MAX)   // 625
#define STAGE_CAP 28                // 625*28*4 = 70 KB -> 2 blocks/CU
#define CHUNK 16                    // flush granularity (64 B, always aligned)
#define SCAT_BLOCKS 512             // 2 blocks per CU
#define SBLOCK 512                  // 8 waves/block -> 16 waves/CU
#define EPB 4                       // edges per thread per batch (2048/batch)
#define BBLOCK 1024                 // binned-edge block: 16 waves/CU
#define SENTINEL 0xFFFFFFFFu
#define OVGUARD 4096u               // max overflow entries per bin (top region)
#define GPAD 16                     // u32 stride between cursors (one 64B line each)

// ws layout:
//   [0      , 16 KB ) : double prox partials (nbins or EDGE_BLOCKS entries)
//   [16 KB  , 24 KB ) : double comp partials (one per node block)
//   [24 KB  , 104 KB) : u32 cursors, line-padded: bottom[b]=gcur[b*16], top[b]=gcur[(nbins+b)*16]
//   [128 KB , +N*8  ) : float2 table[N] (compact x,y per node)
//   [ ...           ) : u32 gbins[nbins][bincap] (routed packed edges)
#define PROX_OFF 0
#define COMP_OFF (16 * 1024)
#define GCUR_OFF (24 * 1024)
#define TABLE_OFF (128 * 1024)

typedef float vfloat2 __attribute__((ext_vector_type(2)));
typedef int vint4 __attribute__((ext_vector_type(4)));
typedef unsigned uvec4 __attribute__((ext_vector_type(4)));

// CK-style asm-declared buffer load (fallback gather path).
__device__ vfloat2 llvm_amdgcn_raw_buffer_load_v2f32(vint4 rsrc, int voffset, int soffset,
                                                     int cpol) __asm("llvm.amdgcn.raw.buffer.load.v2f32");

__device__ __forceinline__ vint4 make_srd(const void* base, unsigned int bytes) {
    union { const void* p; unsigned int w[2]; } pb;
    pb.p = base;
    vint4 r;
    r.x = (int)pb.w[0];
    r.y = (int)pb.w[1];
    r.z = (int)bytes;
    r.w = 0x00020000;
    return r;
}

// ---------------- device helpers ----------------

__device__ __forceinline__ double safe_den(double den) {
    return copysign(fmax(fabs(den), UHG_EPS), den);
}

__device__ __forceinline__ double quad_xy(vfloat2 a, vfloat2 b) {
    double xa = a.x, ya = a.y, xb = b.x, yb = b.y;
    double aa = 1.0 - (xa * xa + ya * ya);
    double bb = 1.0 - (xb * xb + yb * yb);
    double ab = 1.0 - (xa * xb + ya * yb);
    double den = aa * bb;
    double num = ab * ab - den;
    return num / safe_den(den);
}

// Block reduction for up to 16 waves: returns total on thread 0. sh >= 16 doubles.
__device__ __forceinline__ double block_reduce(double v, double* sh) {
    int lane = threadIdx.x & 63;
    int wid = threadIdx.x >> 6;
    v += __shfl_down(v, 32);
    v += __shfl_down(v, 16);
    v += __shfl_down(v, 8);
    v += __shfl_down(v, 4);
    v += __shfl_down(v, 2);
    v += __shfl_down(v, 1);
    if (lane == 0) sh[wid] = v;
    __syncthreads();
    double r = 0.0;
    if (wid == 0) {
        int nw = (int)(blockDim.x >> 6);
        r = (lane < nw) ? sh[lane] : 0.0;
        r += __shfl_down(r, 8);
        r += __shfl_down(r, 4);
        r += __shfl_down(r, 2);
        r += __shfl_down(r, 1);
    }
    __syncthreads();
    return r;
}

// ---------------- kernels ----------------

// Build compact (x,y) table + compactness partials; zero both (padded) cursor arrays.
__global__ __launch_bounds__(BLOCK) void node_kernel(const float* __restrict__ z,
                                                     vfloat2* __restrict__ table,
                                                     double* __restrict__ comp_partials, int N,
                                                     unsigned* __restrict__ gcur, int nbins) {
    __shared__ double sh[16];
    if (gcur && blockIdx.x == 0) {
        for (int j = threadIdx.x; j < 2 * nbins * GPAD; j += BLOCK) gcur[j] = 0u;
    }
    const vfloat2* zp = (const vfloat2*)z;
    double local = 0.0;
    for (int i = blockIdx.x * BLOCK + threadIdx.x; i < N; i += NODE_BLOCKS * BLOCK) {
        vfloat2 v = zp[(size_t)i * (ZDIM / 2)];
        if (table) table[i] = v;
        double x = v.x, y = v.y;
        double aa = 1.0 - (x * x + y * y);
        local += (1.0 - aa) / safe_den(aa);   // ab=1, bb=1 against origin
    }
    double tot = block_reduce(local, sh);
    if (threadIdx.x == 0) comp_partials[blockIdx.x] = tot;
}

// Phase A v3: route edges into bin (src>>13)*P + (dst>>13), payload u32
// (src_local | dst_local<<13). Serialization fixes vs v2:
//  - 2 blocks/CU (70 KB stage) -> 16 waves/CU of latency hiding;
//  - per-batch PROC split into compute-all / atomicAdd-all / store-all so the 4
//    ds_add_rtn issue back-to-back (pipelined returns) instead of 4 serial
//    ~100-cycle chains broken by aliasing LDS stores;
//  - global cursors line-padded (GPAD) to kill cross-XCD false sharing.
__global__ __launch_bounds__(SBLOCK) void scatter_kernel(const int* __restrict__ src,
                                                         const int* __restrict__ dst, int E,
                                                         int P, int nbins,
                                                         unsigned* __restrict__ gcur,
                                                         unsigned* __restrict__ gbins,
                                                         int bincap) {
    __shared__ unsigned cnt[NBINS_MAX];
    __shared__ __align__(16) unsigned stage[NBINS_MAX][STAGE_CAP];   // 70 KB
    const int tid = threadIdx.x;

    for (int b = tid; b < nbins; b += SBLOCK) cnt[b] = 0u;
    __syncthreads();

#define OVFLOW(B, V)                                                                      \
    {                                                                                     \
        unsigned _hp = atomicAdd(&gcur[(size_t)(nbins + (B)) * GPAD], 1u);                \
        if (_hp < OVGUARD) gbins[(size_t)(B) * bincap + (bincap - 1 - (int)_hp)] = (V);   \
    }

    auto flush_bins = [&](bool final_pad) {
        for (int b = tid; b < nbins; b += SBLOCK) {
            unsigned n = cnt[b];
            unsigned m = n < (unsigned)STAGE_CAP ? n : (unsigned)STAGE_CAP;
            while (m >= (unsigned)CHUNK) {
                unsigned pos = atomicAdd(&gcur[(size_t)b * GPAD], (unsigned)CHUNK);
                if (pos + CHUNK <= (unsigned)bincap) {
                    unsigned* out = gbins + (size_t)b * bincap + pos;
#pragma unroll
                    for (int j = 0; j < CHUNK / 4; ++j)
                        *(uvec4*)(out + 4 * j) = *(const uvec4*)&stage[b][4 * j];
                } else {
                    for (int j = 0; j < CHUNK; ++j) OVFLOW(b, stage[b][j]);
                }
                for (unsigned j = CHUNK; j < m; ++j) stage[b][j - CHUNK] = stage[b][j];
                m -= CHUNK;
            }
            if (final_pad && m > 0) {
                for (unsigned j = m; j < (unsigned)CHUNK; ++j) stage[b][j] = SENTINEL;
                unsigned pos = atomicAdd(&gcur[(size_t)b * GPAD], (unsigned)CHUNK);
                if (pos + CHUNK <= (unsigned)bincap) {
                    unsigned* out = gbins + (size_t)b * bincap + pos;
#pragma unroll
                    for (int j = 0; j < CHUNK / 4; ++j)
                        *(uvec4*)(out + 4 * j) = *(const uvec4*)&stage[b][4 * j];
                } else {
                    for (unsigned j = 0; j < m; ++j) OVFLOW(b, stage[b][j]);
                }
                m = 0;
            }
            cnt[b] = m;
        }
    };

    // contiguous per-block edge range, 4-aligned start (last block takes the tail)
    long e0 = ((long)blockIdx.x * E / SCAT_BLOCKS) & ~3L;
    long e1 = (blockIdx.x == SCAT_BLOCKS - 1)
                  ? (long)E
                  : (((long)(blockIdx.x + 1) * E / SCAT_BLOCKS) & ~3L);
    long span = e1 - e0;
    long nbatch = span / (EPB * SBLOCK);        // full 2048-edge batches
    long rem0 = e0 + nbatch * EPB * SBLOCK;

    const vint4* s4 = (const vint4*)(src + e0);
    const vint4* d4 = (const vint4*)(dst + e0);

    vint4 cs = {}, cd = {};
    if (nbatch > 0) {   // prologue: batch 0 indices
        cs = __builtin_nontemporal_load(s4 + tid);
        cd = __builtin_nontemporal_load(d4 + tid);
    }
    for (long k = 0; k < nbatch; ++k) {
        vint4 s = cs, d = cd;
        if (k + 1 < nbatch) {   // prefetch next batch before touching LDS
            cs = __builtin_nontemporal_load(s4 + (k + 1) * SBLOCK + tid);
            cd = __builtin_nontemporal_load(d4 + (k + 1) * SBLOCK + tid);
        }
        __builtin_amdgcn_sched_barrier(0);
        // phase 1: pure VALU — bins & payloads
        int bn0 = (s.x >> PART_SHIFT) * P + (d.x >> PART_SHIFT);
        int bn1 = (s.y >> PART_SHIFT) * P + (d.y >> PART_SHIFT);
        int bn2 = (s.z >> PART_SHIFT) * P + (d.z >> PART_SHIFT);
        int bn3 = (s.w >> PART_SHIFT) * P + (d.w >> PART_SHIFT);
        unsigned vl0 = (unsigned)(s.x & (PART_SIZE - 1)) | ((unsigned)(d.x & (PART_SIZE - 1)) << PART_SHIFT);
        unsigned vl1 = (unsigned)(s.y & (PART_SIZE - 1)) | ((unsigned)(d.y & (PART_SIZE - 1)) << PART_SHIFT);
        unsigned vl2 = (unsigned)(s.z & (PART_SIZE - 1)) | ((unsigned)(d.z & (PART_SIZE - 1)) << PART_SHIFT);
        unsigned vl3 = (unsigned)(s.w & (PART_SIZE - 1)) | ((unsigned)(d.w & (PART_SIZE - 1)) << PART_SHIFT);
        // phase 2: back-to-back ds_add_rtn (no intervening stores -> pipelined)
        unsigned sl0 = atomicAdd(&cnt[bn0], 1u);
        unsigned sl1 = atomicAdd(&cnt[bn1], 1u);
        unsigned sl2 = atomicAdd(&cnt[bn2], 1u);
        unsigned sl3 = atomicAdd(&cnt[bn3], 1u);
        // phase 3: placement
        if (sl0 < (unsigned)STAGE_CAP) stage[bn0][sl0] = vl0; else OVFLOW(bn0, vl0);
        if (sl1 < (unsigned)STAGE_CAP) stage[bn1][sl1] = vl1; else OVFLOW(bn1, vl1);
        if (sl2 < (unsigned)STAGE_CAP) stage[bn2][sl2] = vl2; else OVFLOW(bn2, vl2);
        if (sl3 < (unsigned)STAGE_CAP) stage[bn3][sl3] = vl3; else OVFLOW(bn3, vl3);
        __syncthreads();
        flush_bins(false);
        __syncthreads();
    }
    // remainder edges (scalar)
    for (long i = rem0 + tid; i < e1; i += SBLOCK) {
        int s = src[i], d = dst[i];
        int bn = (s >> PART_SHIFT) * P + (d >> PART_SHIFT);
        unsigned vl = (unsigned)(s & (PART_SIZE - 1)) | ((unsigned)(d & (PART_SIZE - 1)) << PART_SHIFT);
        unsigned sl = atomicAdd(&cnt[bn], 1u);
        if (sl < (unsigned)STAGE_CAP) stage[bn][sl] = vl; else OVFLOW(bn, vl);
    }
    __syncthreads();
    flush_bins(true);   // drain + sentinel-pad residues to full chunks
#undef OVFLOW
}

// Phase B v2: one block per bin, 16 waves. Both endpoint partitions in LDS (128 KB).
// Payload read as uint4 (4 edges / 16 B / instr), software-pipelined one iteration
// ahead so the coalesced stream load never gates the ds_read+fp64 pipeline.
__global__ __launch_bounds__(BBLOCK) void binned_edge_kernel(const vfloat2* __restrict__ table,
                                                             int N, int P,
                                                             const unsigned* __restrict__ gcur,
                                                             const unsigned* __restrict__ gbins,
                                                             int bincap,
                                                             double* __restrict__ prox_partials) {
    __shared__ vfloat2 pts[2][PART_SIZE];   // 128 KB
    __shared__ double sh[16];
    const int bin = blockIdx.x;
    const int sp = bin / P, dp = bin % P;
    const int tid = threadIdx.x;
    const int nbins = P * P;

    for (int j = tid; j < PART_SIZE; j += BBLOCK) {
        int gs = (sp << PART_SHIFT) + j;
        int gd = (dp << PART_SHIFT) + j;
        vfloat2 zv = {0.0f, 0.0f};
        pts[0][j] = (gs < N) ? table[gs] : zv;
        pts[1][j] = (gd < N) ? table[gd] : zv;
    }
    __syncthreads();

    unsigned lo = gcur[(size_t)bin * GPAD];
    if (lo > (unsigned)bincap) lo = (unsigned)bincap;
    unsigned hi = gcur[(size_t)(nbins + bin) * GPAD];
    if (hi > OVGUARD) hi = OVGUARD;
    const unsigned* eb = gbins + (size_t)bin * bincap;
    const uvec4* eb4 = (const uvec4*)eb;

    double local = 0.0;
    unsigned nv = lo >> 2;   // full uint4 groups (bin base is 16B-aligned)
    unsigned i = tid;
    bool have = i < nv;
    uvec4 cur = {};
    if (have) cur = __builtin_nontemporal_load(eb4 + i);
    while (have) {
        unsigned in2 = i + BBLOCK;
        bool hn = in2 < nv;
        uvec4 nxt = {};
        if (hn) nxt = __builtin_nontemporal_load(eb4 + in2);
        __builtin_amdgcn_sched_barrier(0);
        vfloat2 a0 = pts[0][cur.x & (PART_SIZE - 1u)], b0 = pts[1][(cur.x >> PART_SHIFT) & (PART_SIZE - 1u)];
        vfloat2 a1 = pts[0][cur.y & (PART_SIZE - 1u)], b1 = pts[1][(cur.y >> PART_SHIFT) & (PART_SIZE - 1u)];
        vfloat2 a2 = pts[0][cur.z & (PART_SIZE - 1u)], b2 = pts[1][(cur.z >> PART_SHIFT) & (PART_SIZE - 1u)];
        vfloat2 a3 = pts[0][cur.w & (PART_SIZE - 1u)], b3 = pts[1][(cur.w >> PART_SHIFT) & (PART_SIZE - 1u)];
        if (cur.x != SENTINEL) local += quad_xy(a0, b0);
        if (cur.y != SENTINEL) local += quad_xy(a1, b1);
        if (cur.z != SENTINEL) local += quad_xy(a2, b2);
        if (cur.w != SENTINEL) local += quad_xy(a3, b3);
        cur = nxt;
        i = in2;
        have = hn;
    }
    for (unsigned j = (nv << 2) + tid; j < lo; j += BBLOCK) {   // bottom tail
        unsigned v = eb[j];
        if (v != SENTINEL)
            local += quad_xy(pts[0][v & (PART_SIZE - 1u)],
                             pts[1][(v >> PART_SHIFT) & (PART_SIZE - 1u)]);
    }
    for (unsigned j = tid; j < hi; j += BBLOCK) {   // overflow (top) region, no sentinels
        unsigned v = eb[bincap - 1 - (int)j];
        local += quad_xy(pts[0][v & (PART_SIZE - 1u)],
                         pts[1][(v >> PART_SHIFT) & (PART_SIZE - 1u)]);
    }
    double tot = block_reduce(local, sh);
    if (tid == 0) prox_partials[bin] = tot;
}

// -------- fallback gather path (verified round-1 kernel, unchanged) --------
#define GATHER8(dsta, i0, i1)                                                   \
    dsta[0] = llvm_amdgcn_raw_buffer_load_v2f32(srd, (i0).x << SHIFT, 0, 1);    \
    dsta[1] = llvm_amdgcn_raw_buffer_load_v2f32(srd, (i0).y << SHIFT, 0, 1);    \
    dsta[2] = llvm_amdgcn_raw_buffer_load_v2f32(srd, (i0).z << SHIFT, 0, 1);    \
    dsta[3] = llvm_amdgcn_raw_buffer_load_v2f32(srd, (i0).w << SHIFT, 0, 1);    \
    dsta[4] = llvm_amdgcn_raw_buffer_load_v2f32(srd, (i1).x << SHIFT, 0, 1);    \
    dsta[5] = llvm_amdgcn_raw_buffer_load_v2f32(srd, (i1).y << SHIFT, 0, 1);    \
    dsta[6] = llvm_amdgcn_raw_buffer_load_v2f32(srd, (i1).z << SHIFT, 0, 1);    \
    dsta[7] = llvm_amdgcn_raw_buffer_load_v2f32(srd, (i1).w << SHIFT, 0, 1);

template <int COMPACT>
__global__ __launch_bounds__(BLOCK) void edge_kernel(const vint4* __restrict__ src4,
                                                     const vint4* __restrict__ dst4, int nvec,
                                                     const int* __restrict__ src,
                                                     const int* __restrict__ dst, int E,
                                                     const void* __restrict__ xy, int N,
                                                     double* __restrict__ prox_partials) {
    __shared__ double sh[16];
    double local = 0.0;
    int tid = blockIdx.x * BLOCK + threadIdx.x;
    const int gstride = EDGE_BLOCKS * BLOCK;
    const int SHIFT = COMPACT ? 3 : 9;

    vint4 srd = make_srd(xy, COMPACT ? (unsigned int)N * 8u : (unsigned int)N * 512u);

    int nvec2 = nvec / 2;
    int v0 = tid;
    bool p0 = v0 < nvec2;
    int v1 = v0 + gstride;
    bool p1 = v1 < nvec2;

    vint4 is0 = {}, is1 = {}, id0 = {}, id1 = {};
    vfloat2 ca[8] = {}, cb[8] = {};
    vfloat2 na[8] = {}, nb[8] = {};

    if (p0) {
        vint4 s0 = __builtin_nontemporal_load(src4 + 2 * (long)v0);
        vint4 s1 = __builtin_nontemporal_load(src4 + 2 * (long)v0 + 1);
        vint4 d0 = __builtin_nontemporal_load(dst4 + 2 * (long)v0);
        vint4 d1 = __builtin_nontemporal_load(dst4 + 2 * (long)v0 + 1);
        GATHER8(ca, s0, s1);
        GATHER8(cb, d0, d1);
    }
    if (p1) {
        is0 = __builtin_nontemporal_load(src4 + 2 * (long)v1);
        is1 = __builtin_nontemporal_load(src4 + 2 * (long)v1 + 1);
        id0 = __builtin_nontemporal_load(dst4 + 2 * (long)v1);
        id1 = __builtin_nontemporal_load(dst4 + 2 * (long)v1 + 1);
    }

    while (p0) {
        if (p1) {
            GATHER8(na, is0, is1);
            GATHER8(nb, id0, id1);
        }
        int v2 = v1 + gstride;
        bool p2 = v2 < nvec2;
        if (p2) {
            is0 = __builtin_nontemporal_load(src4 + 2 * (long)v2);
            is1 = __builtin_nontemporal_load(src4 + 2 * (long)v2 + 1);
            id0 = __builtin_nontemporal_load(dst4 + 2 * (long)v2);
            id1 = __builtin_nontemporal_load(dst4 + 2 * (long)v2 + 1);
        }
        __builtin_amdgcn_sched_barrier(0);
#pragma unroll
        for (int i = 0; i < 8; ++i) local += quad_xy(ca[i], cb[i]);
#pragma unroll
        for (int i = 0; i < 8; ++i) { ca[i] = na[i]; cb[i] = nb[i]; }
        p0 = p1;
        v1 = v2;
        p1 = p2;
    }

    for (int e = 8 * nvec2 + tid; e < E; e += gstride) {
        vfloat2 a = llvm_amdgcn_raw_buffer_load_v2f32(srd, src[e] << SHIFT, 0, 1);
        vfloat2 b = llvm_amdgcn_raw_buffer_load_v2f32(srd, dst[e] << SHIFT, 0, 1);
        local += quad_xy(a, b);
    }
    double tot = block_reduce(local, sh);
    if (threadIdx.x == 0) prox_partials[blockIdx.x] = tot;
}

// Sum partials + spread over first min(10,E) edges + combine. One block of 256.
__global__ __launch_bounds__(BLOCK) void finalize_kernel(const int* __restrict__ src,
                                                         const int* __restrict__ dst,
                                                         const float* __restrict__ z,
                                                         const double* __restrict__ prox_partials,
                                                         int nprox,
                                                         const double* __restrict__ comp_partials,
                                                         float* __restrict__ out, int N, int E) {
    __shared__ double sh[16];
    int t = threadIdx.x;

    double pl = 0.0;
    for (int i = t; i < nprox; i += BLOCK) pl += prox_partials[i];
    double prox = block_reduce(pl, sh);

    double cl = 0.0;
    for (int i = t; i < NODE_BLOCKS; i += BLOCK) cl += comp_partials[i];
    double comp = block_reduce(cl, sh);

    int n_sp = E < 10 ? E : 10;
    double sl = 0.0;
    if (t < n_sp) {
        int s = src[t], d = dst[t];
        double xa = z[(size_t)s * ZDIM], ya = z[(size_t)s * ZDIM + 1];
        double xb = z[(size_t)d * ZDIM], yb = z[(size_t)d * ZDIM + 1];
        double aa = -(ya * ya + xa * xa);
        double bb = -(yb * yb + xb * xb);
        double ab = -(ya * yb + xa * xb);
        double den = aa * bb;
        sl = (ab * ab - den) / safe_den(den);
    }
    double spread = block_reduce(sl, sh);

    if (t == 0) {
        double loss = prox / (double)E + comp / (double)N;
        if (n_sp > 0) loss += 0.1 * (spread / (double)n_sp);
        out[0] = (float)loss;
    }
}

// ---------------- launch ----------------

extern "C" void kernel_launch(void* const* d_in, const int* in_sizes, int n_in,
                              void* d_out, int out_size, void* d_ws, size_t ws_size,
                              hipStream_t stream) {
    const float* z = (const float*)d_in[0];
    const int* edge_index = (const int*)d_in[1];
    float* out = (float*)d_out;

    const int N = in_sizes[0] / ZDIM;
    const int E = in_sizes[1] / 2;
    const int* src = edge_index;
    const int* dst = edge_index + (size_t)E;

    double* prox_partials = (double*)((char*)d_ws + PROX_OFF);
    double* comp_partials = (double*)((char*)d_ws + COMP_OFF);
    unsigned* gcur = (unsigned*)((char*)d_ws + GCUR_OFF);
    vfloat2* table = (vfloat2*)((char*)d_ws + TABLE_OFF);
    bool use_table = ws_size >= TABLE_OFF + (size_t)N * sizeof(vfloat2);

    // binned-path feasibility (ws-adaptive bincap)
    const int P = (N + PART_SIZE - 1) >> PART_SHIFT;
    const int nbins = P * P;
    size_t gbins_off = TABLE_OFF + (((size_t)N * 8 + 255) & ~(size_t)255);
    bool use_binned = false;
    unsigned* gbins = nullptr;
    int bincap = 0;
    if (use_table && P >= 1 && P <= P_MAX && nbins <= NBINS_MAX && E > nbins * 64 &&
        ws_size > gbins_off) {
        int mean = E / nbins;
        // expected sentinel pad: SCAT_BLOCKS * avg(16-m) ~ 512*8.5 ~ 4400; ~6.5 sigma slack
        int cap_want = (mean + 5504) & ~31;
        int need_min = mean + 5208;
        size_t avail = ws_size - gbins_off;
        int cap_fit = (int)((avail / ((size_t)nbins * 4)) & ~(size_t)31);
        bincap = cap_fit < cap_want ? cap_fit : cap_want;
        if (bincap >= need_min) {
            use_binned = true;
            gbins = (unsigned*)((char*)d_ws + gbins_off);
        }
    }

    node_kernel<<<NODE_BLOCKS, BLOCK, 0, stream>>>(z, use_table ? table : nullptr,
                                                   comp_partials,
                                                   N, use_binned ? gcur : nullptr, nbins);

    if (use_binned) {
        scatter_kernel<<<SCAT_BLOCKS, SBLOCK, 0, stream>>>(src, dst, E, P, nbins, gcur, gbins,
                                                           bincap);
        binned_edge_kernel<<<nbins, BBLOCK, 0, stream>>>(table, N, P, gcur, gbins, bincap,
                                                         prox_partials);
        finalize_kernel<<<1, BLOCK, 0, stream>>>(src, dst, z, prox_partials, nbins,
                                                 comp_partials, out, N, E);
    } else {
        int nvec = E / 4;
        if (use_table) {
            edge_kernel<1><<<EDGE_BLOCKS, BLOCK, 0, stream>>>((const vint4*)src,
                                                              (const vint4*)dst, nvec, src, dst,
                                                              E, table, N, prox_partials);
        } else {
            edge_kernel<0><<<EDGE_BLOCKS, BLOCK, 0, stream>>>((const vint4*)src,
                                                              (const vint4*)dst, nvec, src, dst,
                                                              E, z, N, prox_partials);
        }
        finalize_kernel<<<1, BLOCK, 0, stream>>>(src, dst, z, prox_partials, EDGE_BLOCKS,
                                                 comp_partials, out, N, E);
    }
}